// Round 2
// baseline (835.933 us; speedup 1.0000x reference)
//
#include <hip/hip_runtime.h>
#include <stdint.h>

#define NN 100000
#define NE 1600000

typedef float f4 __attribute__((ext_vector_type(4)));
typedef float f2 __attribute__((ext_vector_type(2)));

// Threefry-2x32, 20 rounds (Random123 / JAX exact).
__host__ __device__ inline void threefry2x32(uint32_t k0, uint32_t k1,
                                             uint32_t x0, uint32_t x1,
                                             uint32_t* y0, uint32_t* y1) {
  uint32_t ks[3] = {k0, k1, k0 ^ k1 ^ 0x1BD11BDAu};
  x0 += ks[0]; x1 += ks[1];
  const uint32_t R[2][4] = {{13u, 15u, 26u, 6u}, {17u, 29u, 16u, 24u}};
#pragma unroll
  for (int i = 0; i < 5; ++i) {
#pragma unroll
    for (int j = 0; j < 4; ++j) {
      uint32_t r = R[i & 1][j];
      x0 += x1;
      x1 = (x1 << r) | (x1 >> (32u - r));
      x1 ^= x0;
    }
    x0 += ks[(i + 1) % 3];
    x1 += ks[(i + 2) % 3] + (uint32_t)(i + 1);
  }
  *y0 = x0; *y1 = x1;
}

// Partitionable-mode 32-bit random bits: xor of the two outputs, counter = (0, idx).
__device__ inline uint32_t tf_bits32(uint32_t k0, uint32_t k1, uint32_t idx) {
  uint32_t a, b;
  threefry2x32(k0, k1, 0u, idx, &a, &b);
  return a ^ b;
}

__global__ void k_init(uint32_t* cnt, uint32_t* fill) {
  int i = blockIdx.x * 256 + threadIdx.x;
  if (i < NN) { cnt[i] = 0u; fill[i] = 0u; }
}

__global__ void k_hist(const int* __restrict__ ei, uint32_t* __restrict__ cnt) {
  int e = blockIdx.x * 256 + threadIdx.x;
  if (e < NE) atomicAdd(&cnt[ei[NE + e]], 1u);
}

__global__ void k_dinv(const uint32_t* __restrict__ cnt, float* __restrict__ dinv) {
  int i = blockIdx.x * 256 + threadIdx.x;
  if (i < NN) dinv[i] = 1.0f / sqrtf((float)(cnt[i] + 1u));
}

// Two-level exclusive scan of cnt[0..NN) -> rp. 1024 elems per block.
__global__ __launch_bounds__(256) void k_scan1(const uint32_t* __restrict__ cnt,
                                               uint32_t* __restrict__ rp,
                                               uint32_t* __restrict__ bsum) {
  __shared__ uint32_t sh[256];
  int t = threadIdx.x;
  int base = blockIdx.x * 1024 + t * 4;
  uint32_t v[4];
  uint32_t s = 0;
#pragma unroll
  for (int i = 0; i < 4; ++i) {
    int idx = base + i;
    v[i] = (idx < NN) ? cnt[idx] : 0u;
    s += v[i];
  }
  sh[t] = s;
  __syncthreads();
  for (int off = 1; off < 256; off <<= 1) {
    uint32_t x = sh[t];
    if (t >= off) x += sh[t - off];
    __syncthreads();
    sh[t] = x;
    __syncthreads();
  }
  uint32_t run = (t > 0) ? sh[t - 1] : 0u;
  if (t == 255) bsum[blockIdx.x] = sh[255];
#pragma unroll
  for (int i = 0; i < 4; ++i) {
    int idx = base + i;
    if (idx < NN) rp[idx] = run;
    run += v[i];
  }
}

__global__ void k_scan2(uint32_t* bsum, int nb) {
  if (threadIdx.x == 0 && blockIdx.x == 0) {
    uint32_t s = 0;
    for (int i = 0; i < nb; ++i) { uint32_t x = bsum[i]; bsum[i] = s; s += x; }
  }
}

__global__ void k_scan3(uint32_t* rp, const uint32_t* __restrict__ bsum) {
  int i = blockIdx.x * 256 + threadIdx.x;
  if (i < NN) rp[i] += bsum[i >> 10];
  if (i == 0) rp[NN] = (uint32_t)NE;
}

__global__ void k_scatter(const int* __restrict__ ei,
                          const uint32_t* __restrict__ rp,
                          uint32_t* __restrict__ fill,
                          int* __restrict__ csrc) {
  int e = blockIdx.x * 256 + threadIdx.x;
  if (e < NE) {
    int s = ei[e];
    int d = ei[NE + e];
    uint32_t pos = rp[d] + atomicAdd(&fill[d], 1u);
    csrc[pos] = s;
  }
}

// C[nrows x DOUT] = A[nrows x 128] @ W[128 x DOUT].  64 rows per block, 256 thr.
template <int DOUT>
__global__ __launch_bounds__(256) void k_gemm(const float* __restrict__ A,
                                              const float* __restrict__ W,
                                              float* __restrict__ C, int nrows) {
  constexpr int CPT = DOUT / 32;  // cols per thread (4 or 2)
  __shared__ float As[64 * 132];  // stride 132 floats: 16B-aligned rows, 2-way bank alias only
  const int tid = threadIdx.x;
  const int row0 = blockIdx.x * 64;
#pragma unroll
  for (int i = 0; i < 8; ++i) {
    int idx = i * 256 + tid;     // float4 index within 64x128 tile
    int r = idx >> 5;
    int c = (idx & 31) << 2;
    int gr = row0 + r;
    f4 val = {0.f, 0.f, 0.f, 0.f};
    if (gr < nrows) val = *(const f4*)(A + (size_t)gr * 128 + c);
    *(f4*)(&As[r * 132 + c]) = val;
  }
  __syncthreads();
  const int ct = tid & 31;
  const int rt = tid >> 5;
  const int c0 = ct * CPT;
  float acc[8][CPT];
#pragma unroll
  for (int i = 0; i < 8; ++i)
#pragma unroll
    for (int c = 0; c < CPT; ++c) acc[i][c] = 0.f;

  for (int k = 0; k < 128; k += 4) {
    f4 a[8];
#pragma unroll
    for (int i = 0; i < 8; ++i) a[i] = *(const f4*)(&As[(rt * 8 + i) * 132 + k]);
    float wv[4][CPT];
#pragma unroll
    for (int j = 0; j < 4; ++j)
#pragma unroll
      for (int c = 0; c < CPT; ++c) wv[j][c] = W[(k + j) * DOUT + c0 + c];
#pragma unroll
    for (int j = 0; j < 4; ++j)
#pragma unroll
      for (int i = 0; i < 8; ++i)
#pragma unroll
        for (int c = 0; c < CPT; ++c)
          acc[i][c] = fmaf(a[i][j], wv[j][c], acc[i][c]);
  }
#pragma unroll
  for (int i = 0; i < 8; ++i) {
    int gr = row0 + rt * 8 + i;
    if (gr < nrows) {
#pragma unroll
      for (int c = 0; c < CPT; ++c) C[(size_t)gr * DOUT + c0 + c] = acc[i][c];
    }
  }
}

// One wave per destination node: CSR gather-sum + self-loop + bias (+ReLU+dropout).
template <int D, bool DROP>
__global__ __launch_bounds__(256) void k_agg(const float* __restrict__ h,
                                             const uint32_t* __restrict__ rp,
                                             const int* __restrict__ csrc,
                                             const float* __restrict__ dinv,
                                             const float* __restrict__ bias,
                                             float* __restrict__ out,
                                             uint32_t k0, uint32_t k1) {
  int wid = blockIdx.x * 4 + (threadIdx.x >> 6);
  if (wid >= NN) return;
  int lane = threadIdx.x & 63;
  uint32_t beg = rp[wid], end = rp[wid + 1];
  float dv = dinv[wid];
  float sn = dv * dv;
  if (D == 128) {
    float a0 = 0.f, a1 = 0.f;
    for (uint32_t u = beg; u < end; ++u) {
      int s = csrc[u];
      float w = dinv[s] * dv;
      f2 hv = *(const f2*)(h + (size_t)s * 128 + lane * 2);
      a0 = fmaf(w, hv[0], a0);
      a1 = fmaf(w, hv[1], a1);
    }
    f2 hs = *(const f2*)(h + (size_t)wid * 128 + lane * 2);
    a0 = fmaf(sn, hs[0], a0) + bias[lane * 2];
    a1 = fmaf(sn, hs[1], a1) + bias[lane * 2 + 1];
    if (DROP) {
      a0 = fmaxf(a0, 0.f);
      a1 = fmaxf(a1, 0.f);
      uint32_t i0 = (uint32_t)wid * 128u + (uint32_t)lane * 2u;
      uint32_t m0 = tf_bits32(k0, k1, i0);
      uint32_t m1 = tf_bits32(k0, k1, i0 + 1u);
      a0 = (m0 & 0x80000000u) ? 0.f : a0 * 2.f;  // keep iff uniform < 0.5 iff MSB==0
      a1 = (m1 & 0x80000000u) ? 0.f : a1 * 2.f;
    }
    f2 res = {a0, a1};
    *(f2*)(out + (size_t)wid * 128 + lane * 2) = res;
  } else {  // D == 64, final layer (no relu/dropout)
    float a0 = 0.f;
    for (uint32_t u = beg; u < end; ++u) {
      int s = csrc[u];
      float w = dinv[s] * dv;
      a0 = fmaf(w, h[(size_t)s * 64 + lane], a0);
    }
    a0 = fmaf(sn, h[(size_t)wid * 64 + lane], a0) + bias[lane];
    out[(size_t)wid * 64 + lane] = a0;
  }
}

extern "C" void kernel_launch(void* const* d_in, const int* in_sizes, int n_in,
                              void* d_out, int out_size, void* d_ws, size_t ws_size,
                              hipStream_t stream) {
  (void)in_sizes; (void)n_in; (void)out_size; (void)ws_size;
  const float* x  = (const float*)d_in[0];
  const float* W1 = (const float*)d_in[1];
  const float* b1 = (const float*)d_in[2];
  const float* W2 = (const float*)d_in[3];
  const float* b2 = (const float*)d_in[4];
  const float* W3 = (const float*)d_in[5];
  const float* b3 = (const float*)d_in[6];
  const int* ei   = (const int*)d_in[7];   // harness passes integer inputs as int32
  float* out = (float*)d_out;

  char* p = (char*)d_ws;
  auto alloc = [&](size_t bytes) -> void* {
    void* r = (void*)p;
    p += (bytes + 255) & ~(size_t)255;
    return r;
  };
  uint32_t* cnt  = (uint32_t*)alloc((size_t)NN * 4);
  uint32_t* fill = (uint32_t*)alloc((size_t)NN * 4);
  float*    dinv = (float*)alloc((size_t)NN * 4);
  uint32_t* rp   = (uint32_t*)alloc((size_t)(NN + 1) * 4);
  uint32_t* bsum = (uint32_t*)alloc(1024);
  int*      csrc = (int*)alloc((size_t)NE * 4);
  float*    bufA = (float*)alloc((size_t)NN * 128 * 4);
  float*    bufB = (float*)alloc((size_t)NN * 128 * 4);

  // JAX: kd1, kd2 = split(key(42)) — partitionable/fold-like split:
  // kd_i = threefry2x32((0,42), (0,i))
  uint32_t kd1a, kd1b, kd2a, kd2b;
  threefry2x32(0u, 42u, 0u, 0u, &kd1a, &kd1b);
  threefry2x32(0u, 42u, 0u, 1u, &kd2a, &kd2b);

  const int gbN = (NN + 255) / 256;
  const int gbE = (NE + 255) / 256;
  const int gbScan = (NN + 1023) / 1024;  // 98
  const int gbGemm = (NN + 63) / 64;      // 1563
  const int gbAgg = (NN + 3) / 4;         // 25000

  k_init<<<gbN, 256, 0, stream>>>(cnt, fill);
  k_hist<<<gbE, 256, 0, stream>>>(ei, cnt);
  k_dinv<<<gbN, 256, 0, stream>>>(cnt, dinv);
  k_scan1<<<gbScan, 256, 0, stream>>>(cnt, rp, bsum);
  k_scan2<<<1, 64, 0, stream>>>(bsum, gbScan);
  k_scan3<<<gbN, 256, 0, stream>>>(rp, bsum);
  k_scatter<<<gbE, 256, 0, stream>>>(ei, rp, fill, csrc);

  k_gemm<128><<<gbGemm, 256, 0, stream>>>(x, W1, bufA, NN);
  k_agg<128, true><<<gbAgg, 256, 0, stream>>>(bufA, rp, csrc, dinv, b1, bufB, kd1a, kd1b);
  k_gemm<128><<<gbGemm, 256, 0, stream>>>(bufB, W2, bufA, NN);
  k_agg<128, true><<<gbAgg, 256, 0, stream>>>(bufA, rp, csrc, dinv, b2, bufB, kd2a, kd2b);
  k_gemm<64><<<gbGemm, 256, 0, stream>>>(bufB, W3, bufA, NN);
  k_agg<64, false><<<gbAgg, 256, 0, stream>>>(bufA, rp, csrc, dinv, b3, out, 0u, 0u);
}

// Round 3
// 629.032 us; speedup vs baseline: 1.3289x; 1.3289x over previous
//
#include <hip/hip_runtime.h>
#include <stdint.h>

#define NN 100000
#define NE 1600000

typedef float f4 __attribute__((ext_vector_type(4)));
typedef float f2 __attribute__((ext_vector_type(2)));
typedef unsigned short us2 __attribute__((ext_vector_type(2)));
typedef unsigned short us4 __attribute__((ext_vector_type(4)));

__device__ inline float bf2f(unsigned short u) {
  return __uint_as_float(((uint32_t)u) << 16);
}
__device__ inline unsigned short f2bf(float f) {  // round-to-nearest-even
  uint32_t u = __float_as_uint(f);
  return (unsigned short)((u + 0x7fffu + ((u >> 16) & 1u)) >> 16);
}

// Threefry-2x32, 20 rounds (Random123 / JAX exact).
__host__ __device__ inline void threefry2x32(uint32_t k0, uint32_t k1,
                                             uint32_t x0, uint32_t x1,
                                             uint32_t* y0, uint32_t* y1) {
  uint32_t ks[3] = {k0, k1, k0 ^ k1 ^ 0x1BD11BDAu};
  x0 += ks[0]; x1 += ks[1];
  const uint32_t R[2][4] = {{13u, 15u, 26u, 6u}, {17u, 29u, 16u, 24u}};
#pragma unroll
  for (int i = 0; i < 5; ++i) {
#pragma unroll
    for (int j = 0; j < 4; ++j) {
      uint32_t r = R[i & 1][j];
      x0 += x1;
      x1 = (x1 << r) | (x1 >> (32u - r));
      x1 ^= x0;
    }
    x0 += ks[(i + 1) % 3];
    x1 += ks[(i + 2) % 3] + (uint32_t)(i + 1);
  }
  *y0 = x0; *y1 = x1;
}

__device__ inline uint32_t tf_bits32(uint32_t k0, uint32_t k1, uint32_t idx) {
  uint32_t a, b;
  threefry2x32(k0, k1, 0u, idx, &a, &b);
  return a ^ b;
}

__global__ void k_init(uint32_t* cnt, uint32_t* fill) {
  int i = blockIdx.x * 256 + threadIdx.x;
  if (i < NN) { cnt[i] = 0u; fill[i] = 0u; }
}

__global__ void k_hist(const int* __restrict__ ei, uint32_t* __restrict__ cnt) {
  int e = blockIdx.x * 256 + threadIdx.x;
  if (e < NE) atomicAdd(&cnt[ei[NE + e]], 1u);
}

__global__ void k_dinv(const uint32_t* __restrict__ cnt, float* __restrict__ dinv) {
  int i = blockIdx.x * 256 + threadIdx.x;
  if (i < NN) dinv[i] = 1.0f / sqrtf((float)(cnt[i] + 1u));
}

__global__ __launch_bounds__(256) void k_scan1(const uint32_t* __restrict__ cnt,
                                               uint32_t* __restrict__ rp,
                                               uint32_t* __restrict__ bsum) {
  __shared__ uint32_t sh[256];
  int t = threadIdx.x;
  int base = blockIdx.x * 1024 + t * 4;
  uint32_t v[4];
  uint32_t s = 0;
#pragma unroll
  for (int i = 0; i < 4; ++i) {
    int idx = base + i;
    v[i] = (idx < NN) ? cnt[idx] : 0u;
    s += v[i];
  }
  sh[t] = s;
  __syncthreads();
  for (int off = 1; off < 256; off <<= 1) {
    uint32_t x = sh[t];
    if (t >= off) x += sh[t - off];
    __syncthreads();
    sh[t] = x;
    __syncthreads();
  }
  uint32_t run = (t > 0) ? sh[t - 1] : 0u;
  if (t == 255) bsum[blockIdx.x] = sh[255];
#pragma unroll
  for (int i = 0; i < 4; ++i) {
    int idx = base + i;
    if (idx < NN) rp[idx] = run;
    run += v[i];
  }
}

__global__ void k_scan2(uint32_t* bsum, int nb) {
  if (threadIdx.x == 0 && blockIdx.x == 0) {
    uint32_t s = 0;
    for (int i = 0; i < nb; ++i) { uint32_t x = bsum[i]; bsum[i] = s; s += x; }
  }
}

__global__ void k_scan3(uint32_t* rp, const uint32_t* __restrict__ bsum) {
  int i = blockIdx.x * 256 + threadIdx.x;
  if (i < NN) rp[i] += bsum[i >> 10];
  if (i == 0) rp[NN] = (uint32_t)NE;
}

__global__ void k_scatter(const int* __restrict__ ei,
                          const uint32_t* __restrict__ rp,
                          uint32_t* __restrict__ fill,
                          int* __restrict__ csrc) {
  int e = blockIdx.x * 256 + threadIdx.x;
  if (e < NE) {
    int s = ei[e];
    int d = ei[NE + e];
    uint32_t pos = rp[d] + atomicAdd(&fill[d], 1u);
    csrc[pos] = s;
  }
}

// C[nrows x DOUT](bf16) = A[nrows x 128](f32) @ W[128 x DOUT](f32). 64 rows/block.
template <int DOUT>
__global__ __launch_bounds__(256) void k_gemm(const float* __restrict__ A,
                                              const float* __restrict__ W,
                                              unsigned short* __restrict__ C,
                                              int nrows) {
  constexpr int CPT = DOUT / 32;  // cols per thread (4 or 2)
  __shared__ float As[64 * 132];
  const int tid = threadIdx.x;
  const int row0 = blockIdx.x * 64;
#pragma unroll
  for (int i = 0; i < 8; ++i) {
    int idx = i * 256 + tid;
    int r = idx >> 5;
    int c = (idx & 31) << 2;
    int gr = row0 + r;
    f4 val = {0.f, 0.f, 0.f, 0.f};
    if (gr < nrows) val = *(const f4*)(A + (size_t)gr * 128 + c);
    *(f4*)(&As[r * 132 + c]) = val;
  }
  __syncthreads();
  const int ct = tid & 31;
  const int rt = tid >> 5;
  const int c0 = ct * CPT;
  float acc[8][CPT];
#pragma unroll
  for (int i = 0; i < 8; ++i)
#pragma unroll
    for (int c = 0; c < CPT; ++c) acc[i][c] = 0.f;

  for (int k = 0; k < 128; k += 4) {
    f4 a[8];
#pragma unroll
    for (int i = 0; i < 8; ++i) a[i] = *(const f4*)(&As[(rt * 8 + i) * 132 + k]);
    float wv[4][CPT];
#pragma unroll
    for (int j = 0; j < 4; ++j)
#pragma unroll
      for (int c = 0; c < CPT; ++c) wv[j][c] = W[(k + j) * DOUT + c0 + c];
#pragma unroll
    for (int j = 0; j < 4; ++j)
#pragma unroll
      for (int i = 0; i < 8; ++i)
#pragma unroll
        for (int c = 0; c < CPT; ++c)
          acc[i][c] = fmaf(a[i][j], wv[j][c], acc[i][c]);
  }
#pragma unroll
  for (int i = 0; i < 8; ++i) {
    int gr = row0 + rt * 8 + i;
    if (gr < nrows) {
      if (CPT == 4) {
        us4 pk;
#pragma unroll
        for (int c = 0; c < 4; ++c) pk[c] = f2bf(acc[i][c]);
        *(us4*)(C + (size_t)gr * DOUT + c0) = pk;
      } else {
        us2 pk;
#pragma unroll
        for (int c = 0; c < CPT; ++c) pk[c] = f2bf(acc[i][c]);
        *(us2*)(C + (size_t)gr * DOUT + c0) = pk;
      }
    }
  }
}

// One wave per destination node: CSR gather-sum (bf16 h) + self-loop + bias (+ReLU+dropout).
template <int D, bool DROP>
__global__ __launch_bounds__(256) void k_agg(const unsigned short* __restrict__ hb,
                                             const uint32_t* __restrict__ rp,
                                             const int* __restrict__ csrc,
                                             const float* __restrict__ dinv,
                                             const float* __restrict__ bias,
                                             float* __restrict__ out,
                                             uint32_t k0, uint32_t k1) {
  int wid = blockIdx.x * 4 + (threadIdx.x >> 6);
  if (wid >= NN) return;
  int lane = threadIdx.x & 63;
  uint32_t beg = rp[wid], end = rp[wid + 1];
  float dv = dinv[wid];
  float sn = dv * dv;
  if (D == 128) {
    float a0 = 0.f, a1 = 0.f, c0 = 0.f, c1 = 0.f;
    uint32_t u = beg;
    for (; u + 2 <= end; u += 2) {
      int s0 = csrc[u], s1 = csrc[u + 1];
      float w0 = dinv[s0] * dv, w1 = dinv[s1] * dv;
      us2 p0 = *(const us2*)(hb + (size_t)s0 * 128 + lane * 2);
      us2 p1 = *(const us2*)(hb + (size_t)s1 * 128 + lane * 2);
      a0 = fmaf(w0, bf2f(p0[0]), a0);
      a1 = fmaf(w0, bf2f(p0[1]), a1);
      c0 = fmaf(w1, bf2f(p1[0]), c0);
      c1 = fmaf(w1, bf2f(p1[1]), c1);
    }
    if (u < end) {
      int s0 = csrc[u];
      float w0 = dinv[s0] * dv;
      us2 p0 = *(const us2*)(hb + (size_t)s0 * 128 + lane * 2);
      a0 = fmaf(w0, bf2f(p0[0]), a0);
      a1 = fmaf(w0, bf2f(p0[1]), a1);
    }
    a0 += c0; a1 += c1;
    us2 ps = *(const us2*)(hb + (size_t)wid * 128 + lane * 2);
    a0 = fmaf(sn, bf2f(ps[0]), a0) + bias[lane * 2];
    a1 = fmaf(sn, bf2f(ps[1]), a1) + bias[lane * 2 + 1];
    if (DROP) {
      a0 = fmaxf(a0, 0.f);
      a1 = fmaxf(a1, 0.f);
      uint32_t i0 = (uint32_t)wid * 128u + (uint32_t)lane * 2u;
      uint32_t m0 = tf_bits32(k0, k1, i0);
      uint32_t m1 = tf_bits32(k0, k1, i0 + 1u);
      a0 = (m0 & 0x80000000u) ? 0.f : a0 * 2.f;  // keep iff uniform < 0.5 iff MSB==0
      a1 = (m1 & 0x80000000u) ? 0.f : a1 * 2.f;
    }
    f2 res = {a0, a1};
    *(f2*)(out + (size_t)wid * 128 + lane * 2) = res;
  } else {  // D == 64, final layer (no relu/dropout)
    float a0 = 0.f, c0 = 0.f;
    uint32_t u = beg;
    for (; u + 2 <= end; u += 2) {
      int s0 = csrc[u], s1 = csrc[u + 1];
      float w0 = dinv[s0] * dv, w1 = dinv[s1] * dv;
      a0 = fmaf(w0, bf2f(hb[(size_t)s0 * 64 + lane]), a0);
      c0 = fmaf(w1, bf2f(hb[(size_t)s1 * 64 + lane]), c0);
    }
    if (u < end) {
      int s0 = csrc[u];
      float w0 = dinv[s0] * dv;
      a0 = fmaf(w0, bf2f(hb[(size_t)s0 * 64 + lane]), a0);
    }
    a0 += c0;
    a0 = fmaf(sn, bf2f(hb[(size_t)wid * 64 + lane]), a0) + bias[lane];
    out[(size_t)wid * 64 + lane] = a0;
  }
}

extern "C" void kernel_launch(void* const* d_in, const int* in_sizes, int n_in,
                              void* d_out, int out_size, void* d_ws, size_t ws_size,
                              hipStream_t stream) {
  (void)in_sizes; (void)n_in; (void)out_size; (void)ws_size;
  const float* x  = (const float*)d_in[0];
  const float* W1 = (const float*)d_in[1];
  const float* b1 = (const float*)d_in[2];
  const float* W2 = (const float*)d_in[3];
  const float* b2 = (const float*)d_in[4];
  const float* W3 = (const float*)d_in[5];
  const float* b3 = (const float*)d_in[6];
  const int* ei   = (const int*)d_in[7];
  float* out = (float*)d_out;

  char* p = (char*)d_ws;
  auto alloc = [&](size_t bytes) -> void* {
    void* r = (void*)p;
    p += (bytes + 255) & ~(size_t)255;
    return r;
  };
  uint32_t* cnt  = (uint32_t*)alloc((size_t)NN * 4);
  uint32_t* fill = (uint32_t*)alloc((size_t)NN * 4);
  float*    dinv = (float*)alloc((size_t)NN * 4);
  uint32_t* rp   = (uint32_t*)alloc((size_t)(NN + 1) * 4);
  uint32_t* bsum = (uint32_t*)alloc(1024);
  int*      csrc = (int*)alloc((size_t)NE * 4);
  float*    hf   = (float*)alloc((size_t)NN * 128 * 4);           // f32 agg outputs (GEMM inputs)
  unsigned short* hb = (unsigned short*)alloc((size_t)NN * 128 * 2);  // bf16 GEMM outputs (gathered)

  uint32_t kd1a, kd1b, kd2a, kd2b;
  threefry2x32(0u, 42u, 0u, 0u, &kd1a, &kd1b);
  threefry2x32(0u, 42u, 0u, 1u, &kd2a, &kd2b);

  const int gbN = (NN + 255) / 256;
  const int gbE = (NE + 255) / 256;
  const int gbScan = (NN + 1023) / 1024;
  const int gbGemm = (NN + 63) / 64;
  const int gbAgg = (NN + 3) / 4;

  k_init<<<gbN, 256, 0, stream>>>(cnt, fill);
  k_hist<<<gbE, 256, 0, stream>>>(ei, cnt);
  k_dinv<<<gbN, 256, 0, stream>>>(cnt, dinv);
  k_scan1<<<gbScan, 256, 0, stream>>>(cnt, rp, bsum);
  k_scan2<<<1, 64, 0, stream>>>(bsum, gbScan);
  k_scan3<<<gbN, 256, 0, stream>>>(rp, bsum);
  k_scatter<<<gbE, 256, 0, stream>>>(ei, rp, fill, csrc);

  k_gemm<128><<<gbGemm, 256, 0, stream>>>(x, W1, hb, NN);
  k_agg<128, true><<<gbAgg, 256, 0, stream>>>(hb, rp, csrc, dinv, b1, hf, kd1a, kd1b);
  k_gemm<128><<<gbGemm, 256, 0, stream>>>(hf, W2, hb, NN);
  k_agg<128, true><<<gbAgg, 256, 0, stream>>>(hb, rp, csrc, dinv, b2, hf, kd2a, kd2b);
  k_gemm<64><<<gbGemm, 256, 0, stream>>>(hf, W3, hb, NN);
  k_agg<64, false><<<gbAgg, 256, 0, stream>>>(hb, rp, csrc, dinv, b3, out, 0u, 0u);
}

// Round 4
// 552.136 us; speedup vs baseline: 1.5140x; 1.1393x over previous
//
#include <hip/hip_runtime.h>
#include <stdint.h>

#define NN 100000
#define NE 1600000

typedef float f4 __attribute__((ext_vector_type(4)));
typedef float f2 __attribute__((ext_vector_type(2)));
typedef unsigned short us2 __attribute__((ext_vector_type(2)));
typedef unsigned short us4 __attribute__((ext_vector_type(4)));

__device__ inline unsigned short f2bf(float f) {  // round-to-nearest-even
  uint32_t u = __float_as_uint(f);
  return (unsigned short)((u + 0x7fffu + ((u >> 16) & 1u)) >> 16);
}

// Threefry-2x32, 20 rounds (Random123 / JAX exact).
__host__ __device__ inline void threefry2x32(uint32_t k0, uint32_t k1,
                                             uint32_t x0, uint32_t x1,
                                             uint32_t* y0, uint32_t* y1) {
  uint32_t ks[3] = {k0, k1, k0 ^ k1 ^ 0x1BD11BDAu};
  x0 += ks[0]; x1 += ks[1];
  const uint32_t R[2][4] = {{13u, 15u, 26u, 6u}, {17u, 29u, 16u, 24u}};
#pragma unroll
  for (int i = 0; i < 5; ++i) {
#pragma unroll
    for (int j = 0; j < 4; ++j) {
      uint32_t r = R[i & 1][j];
      x0 += x1;
      x1 = (x1 << r) | (x1 >> (32u - r));
      x1 ^= x0;
    }
    x0 += ks[(i + 1) % 3];
    x1 += ks[(i + 2) % 3] + (uint32_t)(i + 1);
  }
  *y0 = x0; *y1 = x1;
}

__device__ inline uint32_t tf_bits32(uint32_t k0, uint32_t k1, uint32_t idx) {
  uint32_t a, b;
  threefry2x32(k0, k1, 0u, idx, &a, &b);
  return a ^ b;
}

__global__ void k_init(uint32_t* cnt) {
  int i = blockIdx.x * 256 + threadIdx.x;
  if (i < NN) cnt[i] = 0u;
}

// Histogram + per-edge slot assignment (single atomic per edge, coalesced slot store).
__global__ void k_hist(const int* __restrict__ ei, uint32_t* __restrict__ cnt,
                       int* __restrict__ slot) {
  int e = blockIdx.x * 256 + threadIdx.x;
  if (e < NE) {
    int d = ei[NE + e];
    slot[e] = (int)atomicAdd(&cnt[d], 1u);
  }
}

__global__ void k_dinv(const uint32_t* __restrict__ cnt, float* __restrict__ dinv) {
  int i = blockIdx.x * 256 + threadIdx.x;
  if (i < NN) dinv[i] = 1.0f / sqrtf((float)(cnt[i] + 1u));
}

__global__ __launch_bounds__(256) void k_scan1(const uint32_t* __restrict__ cnt,
                                               uint32_t* __restrict__ rp,
                                               uint32_t* __restrict__ bsum) {
  __shared__ uint32_t sh[256];
  int t = threadIdx.x;
  int base = blockIdx.x * 1024 + t * 4;
  uint32_t v[4];
  uint32_t s = 0;
#pragma unroll
  for (int i = 0; i < 4; ++i) {
    int idx = base + i;
    v[i] = (idx < NN) ? cnt[idx] : 0u;
    s += v[i];
  }
  sh[t] = s;
  __syncthreads();
  for (int off = 1; off < 256; off <<= 1) {
    uint32_t x = sh[t];
    if (t >= off) x += sh[t - off];
    __syncthreads();
    sh[t] = x;
    __syncthreads();
  }
  uint32_t run = (t > 0) ? sh[t - 1] : 0u;
  if (t == 255) bsum[blockIdx.x] = sh[255];
#pragma unroll
  for (int i = 0; i < 4; ++i) {
    int idx = base + i;
    if (idx < NN) rp[idx] = run;
    run += v[i];
  }
}

__global__ void k_scan2(uint32_t* bsum, int nb) {
  if (threadIdx.x == 0 && blockIdx.x == 0) {
    uint32_t s = 0;
    for (int i = 0; i < nb; ++i) { uint32_t x = bsum[i]; bsum[i] = s; s += x; }
  }
}

__global__ void k_scan3(uint32_t* rp, const uint32_t* __restrict__ bsum) {
  int i = blockIdx.x * 256 + threadIdx.x;
  if (i < NN) rp[i] += bsum[i >> 10];
  if (i == 0) rp[NN] = (uint32_t)NE;
}

// No atomics: pos = rp[d] + slot[e]; ei/slot reads coalesced.
__global__ void k_scatter(const int* __restrict__ ei,
                          const uint32_t* __restrict__ rp,
                          const int* __restrict__ slot,
                          int* __restrict__ csrc) {
  int e = blockIdx.x * 256 + threadIdx.x;
  if (e < NE) {
    int s = ei[e];
    int d = ei[NE + e];
    csrc[rp[d] + (uint32_t)slot[e]] = s;
  }
}

// C[nrows x DOUT](bf16) = A[nrows x 128](f32) @ W[128 x DOUT](f32). 64 rows/block.
template <int DOUT>
__global__ __launch_bounds__(256) void k_gemm(const float* __restrict__ A,
                                              const float* __restrict__ W,
                                              unsigned short* __restrict__ C,
                                              int nrows) {
  constexpr int CPT = DOUT / 32;  // cols per thread (4 or 2)
  __shared__ float As[64 * 132];
  const int tid = threadIdx.x;
  const int row0 = blockIdx.x * 64;
#pragma unroll
  for (int i = 0; i < 8; ++i) {
    int idx = i * 256 + tid;
    int r = idx >> 5;
    int c = (idx & 31) << 2;
    int gr = row0 + r;
    f4 val = {0.f, 0.f, 0.f, 0.f};
    if (gr < nrows) val = *(const f4*)(A + (size_t)gr * 128 + c);
    *(f4*)(&As[r * 132 + c]) = val;
  }
  __syncthreads();
  const int ct = tid & 31;
  const int rt = tid >> 5;
  const int c0 = ct * CPT;
  float acc[8][CPT];
#pragma unroll
  for (int i = 0; i < 8; ++i)
#pragma unroll
    for (int c = 0; c < CPT; ++c) acc[i][c] = 0.f;

  for (int k = 0; k < 128; k += 4) {
    f4 a[8];
#pragma unroll
    for (int i = 0; i < 8; ++i) a[i] = *(const f4*)(&As[(rt * 8 + i) * 132 + k]);
    float wv[4][CPT];
#pragma unroll
    for (int j = 0; j < 4; ++j)
#pragma unroll
      for (int c = 0; c < CPT; ++c) wv[j][c] = W[(k + j) * DOUT + c0 + c];
#pragma unroll
    for (int j = 0; j < 4; ++j)
#pragma unroll
      for (int i = 0; i < 8; ++i)
#pragma unroll
        for (int c = 0; c < CPT; ++c)
          acc[i][c] = fmaf(a[i][j], wv[j][c], acc[i][c]);
  }
#pragma unroll
  for (int i = 0; i < 8; ++i) {
    int gr = row0 + rt * 8 + i;
    if (gr < nrows) {
      if (CPT == 4) {
        us4 pk;
#pragma unroll
        for (int c = 0; c < 4; ++c) pk[c] = f2bf(acc[i][c]);
        *(us4*)(C + (size_t)gr * DOUT + c0) = pk;
      } else {
        us2 pk;
#pragma unroll
        for (int c = 0; c < CPT; ++c) pk[c] = f2bf(acc[i][c]);
        *(us2*)(C + (size_t)gr * DOUT + c0) = pk;
      }
    }
  }
}

// One wave per destination node: CSR gather-sum (bf16 h, scalarized addressing)
// + self-loop + bias (+ReLU+dropout).
template <int D, bool DROP>
__global__ __launch_bounds__(256) void k_agg(const unsigned short* __restrict__ hb,
                                             const uint32_t* __restrict__ rp,
                                             const int* __restrict__ csrc,
                                             const float* __restrict__ dinv,
                                             const float* __restrict__ bias,
                                             float* __restrict__ out,
                                             uint32_t k0, uint32_t k1) {
  int wid = blockIdx.x * 4 + (threadIdx.x >> 6);
  if (wid >= NN) return;
  int lane = threadIdx.x & 63;
  uint32_t beg = rp[wid], end = rp[wid + 1];
  float dv = dinv[wid];
  float sn = dv * dv;
  const char* hbase = (const char*)hb;
  if (D == 128) {
    const uint32_t loff = (uint32_t)(lane << 2);  // byte offset within 256B row
    float a0 = 0.f, a1 = 0.f, c0 = 0.f, c1 = 0.f;
    uint32_t u = beg;
    for (; u + 2 <= end; u += 2) {
      int s0 = __builtin_amdgcn_readfirstlane(csrc[u]);
      int s1 = __builtin_amdgcn_readfirstlane(csrc[u + 1]);
      float w0 = dinv[s0] * dv;
      float w1 = dinv[s1] * dv;
      uint32_t q0 = *(const uint32_t*)(hbase + (((uint32_t)s0 << 8) + loff));
      uint32_t q1 = *(const uint32_t*)(hbase + (((uint32_t)s1 << 8) + loff));
      a0 = fmaf(w0, __uint_as_float(q0 << 16), a0);
      a1 = fmaf(w0, __uint_as_float(q0 & 0xffff0000u), a1);
      c0 = fmaf(w1, __uint_as_float(q1 << 16), c0);
      c1 = fmaf(w1, __uint_as_float(q1 & 0xffff0000u), c1);
    }
    if (u < end) {
      int s0 = __builtin_amdgcn_readfirstlane(csrc[u]);
      float w0 = dinv[s0] * dv;
      uint32_t q0 = *(const uint32_t*)(hbase + (((uint32_t)s0 << 8) + loff));
      a0 = fmaf(w0, __uint_as_float(q0 << 16), a0);
      a1 = fmaf(w0, __uint_as_float(q0 & 0xffff0000u), a1);
    }
    a0 += c0; a1 += c1;
    uint32_t qs = *(const uint32_t*)(hbase + (((uint32_t)wid << 8) + loff));
    f2 bv = *(const f2*)(bias + lane * 2);
    a0 = fmaf(sn, __uint_as_float(qs << 16), a0) + bv[0];
    a1 = fmaf(sn, __uint_as_float(qs & 0xffff0000u), a1) + bv[1];
    if (DROP) {
      a0 = fmaxf(a0, 0.f);
      a1 = fmaxf(a1, 0.f);
      uint32_t i0 = (uint32_t)wid * 128u + (uint32_t)lane * 2u;
      uint32_t m0 = tf_bits32(k0, k1, i0);
      uint32_t m1 = tf_bits32(k0, k1, i0 + 1u);
      a0 = (m0 & 0x80000000u) ? 0.f : a0 * 2.f;  // keep iff uniform < 0.5 iff MSB==0
      a1 = (m1 & 0x80000000u) ? 0.f : a1 * 2.f;
    }
    f2 res = {a0, a1};
    *(f2*)(out + (size_t)wid * 128 + lane * 2) = res;
  } else {  // D == 64, final layer (no relu/dropout)
    const uint32_t loff = (uint32_t)(lane << 1);  // byte offset within 128B row
    float a0 = 0.f, c0 = 0.f;
    uint32_t u = beg;
    for (; u + 2 <= end; u += 2) {
      int s0 = __builtin_amdgcn_readfirstlane(csrc[u]);
      int s1 = __builtin_amdgcn_readfirstlane(csrc[u + 1]);
      float w0 = dinv[s0] * dv;
      float w1 = dinv[s1] * dv;
      uint32_t q0 = (uint32_t)*(const unsigned short*)(hbase + (((uint32_t)s0 << 7) + loff));
      uint32_t q1 = (uint32_t)*(const unsigned short*)(hbase + (((uint32_t)s1 << 7) + loff));
      a0 = fmaf(w0, __uint_as_float(q0 << 16), a0);
      c0 = fmaf(w1, __uint_as_float(q1 << 16), c0);
    }
    if (u < end) {
      int s0 = __builtin_amdgcn_readfirstlane(csrc[u]);
      float w0 = dinv[s0] * dv;
      uint32_t q0 = (uint32_t)*(const unsigned short*)(hbase + (((uint32_t)s0 << 7) + loff));
      a0 = fmaf(w0, __uint_as_float(q0 << 16), a0);
    }
    a0 += c0;
    uint32_t qs = (uint32_t)*(const unsigned short*)(hbase + (((uint32_t)wid << 7) + loff));
    a0 = fmaf(sn, __uint_as_float(qs << 16), a0) + bias[lane];
    out[(size_t)wid * 64 + lane] = a0;
  }
}

extern "C" void kernel_launch(void* const* d_in, const int* in_sizes, int n_in,
                              void* d_out, int out_size, void* d_ws, size_t ws_size,
                              hipStream_t stream) {
  (void)in_sizes; (void)n_in; (void)out_size; (void)ws_size;
  const float* x  = (const float*)d_in[0];
  const float* W1 = (const float*)d_in[1];
  const float* b1 = (const float*)d_in[2];
  const float* W2 = (const float*)d_in[3];
  const float* b2 = (const float*)d_in[4];
  const float* W3 = (const float*)d_in[5];
  const float* b3 = (const float*)d_in[6];
  const int* ei   = (const int*)d_in[7];
  float* out = (float*)d_out;

  char* p = (char*)d_ws;
  auto alloc = [&](size_t bytes) -> void* {
    void* r = (void*)p;
    p += (bytes + 255) & ~(size_t)255;
    return r;
  };
  uint32_t* cnt  = (uint32_t*)alloc((size_t)NN * 4);
  float*    dinv = (float*)alloc((size_t)NN * 4);
  uint32_t* rp   = (uint32_t*)alloc((size_t)(NN + 1) * 4);
  uint32_t* bsum = (uint32_t*)alloc(1024);
  int*      slot = (int*)alloc((size_t)NE * 4);
  int*      csrc = (int*)alloc((size_t)NE * 4);
  float*    hf   = (float*)alloc((size_t)NN * 128 * 4);            // f32 agg outputs (GEMM inputs)
  unsigned short* hb = (unsigned short*)alloc((size_t)NN * 128 * 2);  // bf16 GEMM outputs (gathered)

  uint32_t kd1a, kd1b, kd2a, kd2b;
  threefry2x32(0u, 42u, 0u, 0u, &kd1a, &kd1b);
  threefry2x32(0u, 42u, 0u, 1u, &kd2a, &kd2b);

  const int gbN = (NN + 255) / 256;
  const int gbE = (NE + 255) / 256;
  const int gbScan = (NN + 1023) / 1024;
  const int gbGemm = (NN + 63) / 64;
  const int gbAgg = (NN + 3) / 4;

  k_init<<<gbN, 256, 0, stream>>>(cnt);
  k_hist<<<gbE, 256, 0, stream>>>(ei, cnt, slot);
  k_dinv<<<gbN, 256, 0, stream>>>(cnt, dinv);
  k_scan1<<<gbScan, 256, 0, stream>>>(cnt, rp, bsum);
  k_scan2<<<1, 64, 0, stream>>>(bsum, gbScan);
  k_scan3<<<gbN, 256, 0, stream>>>(rp, bsum);
  k_scatter<<<gbE, 256, 0, stream>>>(ei, rp, slot, csrc);

  k_gemm<128><<<gbGemm, 256, 0, stream>>>(x, W1, hb, NN);
  k_agg<128, true><<<gbAgg, 256, 0, stream>>>(hb, rp, csrc, dinv, b1, hf, kd1a, kd1b);
  k_gemm<128><<<gbGemm, 256, 0, stream>>>(hf, W2, hb, NN);
  k_agg<128, true><<<gbAgg, 256, 0, stream>>>(hb, rp, csrc, dinv, b2, hf, kd2a, kd2b);
  k_gemm<64><<<gbGemm, 256, 0, stream>>>(hf, W3, hb, NN);
  k_agg<64, false><<<gbAgg, 256, 0, stream>>>(hb, rp, csrc, dinv, b3, out, 0u, 0u);
}

// Round 5
// 491.389 us; speedup vs baseline: 1.7012x; 1.1236x over previous
//
#include <hip/hip_runtime.h>
#include <stdint.h>

#define NN 100000
#define NE 1600000

typedef float f4 __attribute__((ext_vector_type(4)));
typedef float f2 __attribute__((ext_vector_type(2)));
typedef unsigned short us2 __attribute__((ext_vector_type(2)));
typedef unsigned short us4 __attribute__((ext_vector_type(4)));

__device__ inline unsigned short f2bf(float f) {  // round-to-nearest-even
  uint32_t u = __float_as_uint(f);
  return (unsigned short)((u + 0x7fffu + ((u >> 16) & 1u)) >> 16);
}

// Threefry-2x32, 20 rounds (Random123 / JAX exact).
__host__ __device__ inline void threefry2x32(uint32_t k0, uint32_t k1,
                                             uint32_t x0, uint32_t x1,
                                             uint32_t* y0, uint32_t* y1) {
  uint32_t ks[3] = {k0, k1, k0 ^ k1 ^ 0x1BD11BDAu};
  x0 += ks[0]; x1 += ks[1];
  const uint32_t R[2][4] = {{13u, 15u, 26u, 6u}, {17u, 29u, 16u, 24u}};
#pragma unroll
  for (int i = 0; i < 5; ++i) {
#pragma unroll
    for (int j = 0; j < 4; ++j) {
      uint32_t r = R[i & 1][j];
      x0 += x1;
      x1 = (x1 << r) | (x1 >> (32u - r));
      x1 ^= x0;
    }
    x0 += ks[(i + 1) % 3];
    x1 += ks[(i + 2) % 3] + (uint32_t)(i + 1);
  }
  *y0 = x0; *y1 = x1;
}

__device__ inline uint32_t tf_bits32(uint32_t k0, uint32_t k1, uint32_t idx) {
  uint32_t a, b;
  threefry2x32(k0, k1, 0u, idx, &a, &b);
  return a ^ b;
}

__global__ void k_init(uint32_t* cnt) {
  int i = blockIdx.x * 256 + threadIdx.x;
  if (i < NN) cnt[i] = 0u;
}

// Histogram + per-edge slot assignment (single atomic per edge, coalesced slot store).
__global__ void k_hist(const int* __restrict__ ei, uint32_t* __restrict__ cnt,
                       int* __restrict__ slot) {
  int e = blockIdx.x * 256 + threadIdx.x;
  if (e < NE) {
    int d = ei[NE + e];
    slot[e] = (int)atomicAdd(&cnt[d], 1u);
  }
}

__global__ void k_dinv(const uint32_t* __restrict__ cnt, float* __restrict__ dinv) {
  int i = blockIdx.x * 256 + threadIdx.x;
  if (i < NN) dinv[i] = 1.0f / sqrtf((float)(cnt[i] + 1u));
}

__global__ __launch_bounds__(256) void k_scan1(const uint32_t* __restrict__ cnt,
                                               uint32_t* __restrict__ rp,
                                               uint32_t* __restrict__ bsum) {
  __shared__ uint32_t sh[256];
  int t = threadIdx.x;
  int base = blockIdx.x * 1024 + t * 4;
  uint32_t v[4];
  uint32_t s = 0;
#pragma unroll
  for (int i = 0; i < 4; ++i) {
    int idx = base + i;
    v[i] = (idx < NN) ? cnt[idx] : 0u;
    s += v[i];
  }
  sh[t] = s;
  __syncthreads();
  for (int off = 1; off < 256; off <<= 1) {
    uint32_t x = sh[t];
    if (t >= off) x += sh[t - off];
    __syncthreads();
    sh[t] = x;
    __syncthreads();
  }
  uint32_t run = (t > 0) ? sh[t - 1] : 0u;
  if (t == 255) bsum[blockIdx.x] = sh[255];
#pragma unroll
  for (int i = 0; i < 4; ++i) {
    int idx = base + i;
    if (idx < NN) rp[idx] = run;
    run += v[i];
  }
}

__global__ void k_scan2(uint32_t* bsum, int nb) {
  if (threadIdx.x == 0 && blockIdx.x == 0) {
    uint32_t s = 0;
    for (int i = 0; i < nb; ++i) { uint32_t x = bsum[i]; bsum[i] = s; s += x; }
  }
}

__global__ void k_scan3(uint32_t* rp, const uint32_t* __restrict__ bsum) {
  int i = blockIdx.x * 256 + threadIdx.x;
  if (i < NN) rp[i] += bsum[i >> 10];
  if (i == 0) rp[NN] = (uint32_t)NE;
}

// No atomics: pos = rp[d] + slot[e]; ei/slot reads coalesced.
__global__ void k_scatter(const int* __restrict__ ei,
                          const uint32_t* __restrict__ rp,
                          const int* __restrict__ slot,
                          int* __restrict__ csrc) {
  int e = blockIdx.x * 256 + threadIdx.x;
  if (e < NE) {
    int s = ei[e];
    int d = ei[NE + e];
    csrc[rp[d] + (uint32_t)slot[e]] = s;
  }
}

// C[nrows x DOUT](bf16) = A[nrows x 128](f32) @ W[128 x DOUT](f32). 64 rows/block.
template <int DOUT>
__global__ __launch_bounds__(256) void k_gemm(const float* __restrict__ A,
                                              const float* __restrict__ W,
                                              unsigned short* __restrict__ C,
                                              int nrows) {
  constexpr int CPT = DOUT / 32;  // cols per thread (4 or 2)
  __shared__ float As[64 * 132];
  const int tid = threadIdx.x;
  const int row0 = blockIdx.x * 64;
#pragma unroll
  for (int i = 0; i < 8; ++i) {
    int idx = i * 256 + tid;
    int r = idx >> 5;
    int c = (idx & 31) << 2;
    int gr = row0 + r;
    f4 val = {0.f, 0.f, 0.f, 0.f};
    if (gr < nrows) val = *(const f4*)(A + (size_t)gr * 128 + c);
    *(f4*)(&As[r * 132 + c]) = val;
  }
  __syncthreads();
  const int ct = tid & 31;
  const int rt = tid >> 5;
  const int c0 = ct * CPT;
  float acc[8][CPT];
#pragma unroll
  for (int i = 0; i < 8; ++i)
#pragma unroll
    for (int c = 0; c < CPT; ++c) acc[i][c] = 0.f;

  for (int k = 0; k < 128; k += 4) {
    f4 a[8];
#pragma unroll
    for (int i = 0; i < 8; ++i) a[i] = *(const f4*)(&As[(rt * 8 + i) * 132 + k]);
    float wv[4][CPT];
#pragma unroll
    for (int j = 0; j < 4; ++j) {
      if (CPT == 4) {
        f4 wl = *(const f4*)(W + (size_t)(k + j) * DOUT + c0);
#pragma unroll
        for (int c = 0; c < 4; ++c) wv[j][c] = wl[c];
      } else {
        f2 wl = *(const f2*)(W + (size_t)(k + j) * DOUT + c0);
#pragma unroll
        for (int c = 0; c < CPT; ++c) wv[j][c] = wl[c];
      }
    }
#pragma unroll
    for (int j = 0; j < 4; ++j)
#pragma unroll
      for (int i = 0; i < 8; ++i)
#pragma unroll
        for (int c = 0; c < CPT; ++c)
          acc[i][c] = fmaf(a[i][j], wv[j][c], acc[i][c]);
  }
#pragma unroll
  for (int i = 0; i < 8; ++i) {
    int gr = row0 + rt * 8 + i;
    if (gr < nrows) {
      if (CPT == 4) {
        us4 pk;
#pragma unroll
        for (int c = 0; c < 4; ++c) pk[c] = f2bf(acc[i][c]);
        *(us4*)(C + (size_t)gr * DOUT + c0) = pk;
      } else {
        us2 pk;
#pragma unroll
        for (int c = 0; c < CPT; ++c) pk[c] = f2bf(acc[i][c]);
        *(us2*)(C + (size_t)gr * DOUT + c0) = pk;
      }
    }
  }
}

// One wave per destination node. Batch-load up to 64 edge ids coalesced + their
// dinv in one parallel gather; broadcast per edge via v_readlane into SGPRs so
// the row gather is saddr-form with back-to-back independent issues.
template <int D, bool DROP>
__global__ __launch_bounds__(256) void k_agg(const unsigned short* __restrict__ hb,
                                             const uint32_t* __restrict__ rp,
                                             const int* __restrict__ csrc,
                                             const float* __restrict__ dinv,
                                             const float* __restrict__ bias,
                                             float* __restrict__ out,
                                             uint32_t k0, uint32_t k1) {
  int wid = blockIdx.x * 4 + (threadIdx.x >> 6);
  if (wid >= NN) return;
  int lane = threadIdx.x & 63;
  uint32_t beg = rp[wid], end = rp[wid + 1];
  float dv = dinv[wid];
  float sn = dv * dv;
  const char* hbase = (const char*)hb;

  float a0 = 0.f, a1 = 0.f, c0 = 0.f, c1 = 0.f;

  for (uint32_t u0 = beg; u0 < end; u0 += 64) {
    uint32_t nu = end - u0;
    if (nu > 64u) nu = 64u;
    uint32_t idxl = u0 + (uint32_t)lane;
    uint32_t last = end - 1u;
    if (idxl > last) idxl = last;
    int eidx = csrc[idxl];              // coalesced batch load of edge ids
    float wv = dinv[eidx] * dv;         // 64 random 4B gathers in parallel

    uint32_t j = 0;
    if (D == 128) {
      for (; j + 2 <= nu; j += 2) {
        int s0 = __builtin_amdgcn_readlane(eidx, (int)j);
        int s1 = __builtin_amdgcn_readlane(eidx, (int)(j + 1));
        float w0 = __uint_as_float((uint32_t)__builtin_amdgcn_readlane(
            (int)__float_as_uint(wv), (int)j));
        float w1 = __uint_as_float((uint32_t)__builtin_amdgcn_readlane(
            (int)__float_as_uint(wv), (int)(j + 1)));
        const uint32_t* r0 = (const uint32_t*)(hbase + ((size_t)(uint32_t)s0 << 8));
        const uint32_t* r1 = (const uint32_t*)(hbase + ((size_t)(uint32_t)s1 << 8));
        uint32_t q0 = r0[lane];
        uint32_t q1 = r1[lane];
        a0 = fmaf(w0, __uint_as_float(q0 << 16), a0);
        a1 = fmaf(w0, __uint_as_float(q0 & 0xffff0000u), a1);
        c0 = fmaf(w1, __uint_as_float(q1 << 16), c0);
        c1 = fmaf(w1, __uint_as_float(q1 & 0xffff0000u), c1);
      }
      if (j < nu) {
        int s0 = __builtin_amdgcn_readlane(eidx, (int)j);
        float w0 = __uint_as_float((uint32_t)__builtin_amdgcn_readlane(
            (int)__float_as_uint(wv), (int)j));
        const uint32_t* r0 = (const uint32_t*)(hbase + ((size_t)(uint32_t)s0 << 8));
        uint32_t q0 = r0[lane];
        a0 = fmaf(w0, __uint_as_float(q0 << 16), a0);
        a1 = fmaf(w0, __uint_as_float(q0 & 0xffff0000u), a1);
      }
    } else {  // D == 64
      for (; j + 2 <= nu; j += 2) {
        int s0 = __builtin_amdgcn_readlane(eidx, (int)j);
        int s1 = __builtin_amdgcn_readlane(eidx, (int)(j + 1));
        float w0 = __uint_as_float((uint32_t)__builtin_amdgcn_readlane(
            (int)__float_as_uint(wv), (int)j));
        float w1 = __uint_as_float((uint32_t)__builtin_amdgcn_readlane(
            (int)__float_as_uint(wv), (int)(j + 1)));
        const unsigned short* r0 =
            (const unsigned short*)(hbase + ((size_t)(uint32_t)s0 << 7));
        const unsigned short* r1 =
            (const unsigned short*)(hbase + ((size_t)(uint32_t)s1 << 7));
        uint32_t q0 = (uint32_t)r0[lane];
        uint32_t q1 = (uint32_t)r1[lane];
        a0 = fmaf(w0, __uint_as_float(q0 << 16), a0);
        c0 = fmaf(w1, __uint_as_float(q1 << 16), c0);
      }
      if (j < nu) {
        int s0 = __builtin_amdgcn_readlane(eidx, (int)j);
        float w0 = __uint_as_float((uint32_t)__builtin_amdgcn_readlane(
            (int)__float_as_uint(wv), (int)j));
        const unsigned short* r0 =
            (const unsigned short*)(hbase + ((size_t)(uint32_t)s0 << 7));
        uint32_t q0 = (uint32_t)r0[lane];
        a0 = fmaf(w0, __uint_as_float(q0 << 16), a0);
      }
    }
  }

  if (D == 128) {
    a0 += c0; a1 += c1;
    uint32_t qs = *(const uint32_t*)(hbase + (((size_t)(uint32_t)wid << 8) +
                                              (uint32_t)(lane << 2)));
    f2 bv = *(const f2*)(bias + lane * 2);
    a0 = fmaf(sn, __uint_as_float(qs << 16), a0) + bv[0];
    a1 = fmaf(sn, __uint_as_float(qs & 0xffff0000u), a1) + bv[1];
    if (DROP) {
      a0 = fmaxf(a0, 0.f);
      a1 = fmaxf(a1, 0.f);
      uint32_t i0 = (uint32_t)wid * 128u + (uint32_t)lane * 2u;
      uint32_t m0 = tf_bits32(k0, k1, i0);
      uint32_t m1 = tf_bits32(k0, k1, i0 + 1u);
      a0 = (m0 & 0x80000000u) ? 0.f : a0 * 2.f;  // keep iff uniform < 0.5 iff MSB==0
      a1 = (m1 & 0x80000000u) ? 0.f : a1 * 2.f;
    }
    f2 res = {a0, a1};
    *(f2*)(out + (size_t)wid * 128 + lane * 2) = res;
  } else {
    a0 += c0;
    uint32_t qs = (uint32_t)*(const unsigned short*)(
        hbase + (((size_t)(uint32_t)wid << 7) + (uint32_t)(lane << 1)));
    a0 = fmaf(sn, __uint_as_float(qs << 16), a0) + bias[lane];
    out[(size_t)wid * 64 + lane] = a0;
  }
}

extern "C" void kernel_launch(void* const* d_in, const int* in_sizes, int n_in,
                              void* d_out, int out_size, void* d_ws, size_t ws_size,
                              hipStream_t stream) {
  (void)in_sizes; (void)n_in; (void)out_size; (void)ws_size;
  const float* x  = (const float*)d_in[0];
  const float* W1 = (const float*)d_in[1];
  const float* b1 = (const float*)d_in[2];
  const float* W2 = (const float*)d_in[3];
  const float* b2 = (const float*)d_in[4];
  const float* W3 = (const float*)d_in[5];
  const float* b3 = (const float*)d_in[6];
  const int* ei   = (const int*)d_in[7];
  float* out = (float*)d_out;

  char* p = (char*)d_ws;
  auto alloc = [&](size_t bytes) -> void* {
    void* r = (void*)p;
    p += (bytes + 255) & ~(size_t)255;
    return r;
  };
  uint32_t* cnt  = (uint32_t*)alloc((size_t)NN * 4);
  float*    dinv = (float*)alloc((size_t)NN * 4);
  uint32_t* rp   = (uint32_t*)alloc((size_t)(NN + 1) * 4);
  uint32_t* bsum = (uint32_t*)alloc(1024);
  int*      slot = (int*)alloc((size_t)NE * 4);
  int*      csrc = (int*)alloc((size_t)NE * 4);
  float*    hf   = (float*)alloc((size_t)NN * 128 * 4);            // f32 agg outputs (GEMM inputs)
  unsigned short* hb = (unsigned short*)alloc((size_t)NN * 128 * 2);  // bf16 GEMM outputs (gathered)

  uint32_t kd1a, kd1b, kd2a, kd2b;
  threefry2x32(0u, 42u, 0u, 0u, &kd1a, &kd1b);
  threefry2x32(0u, 42u, 0u, 1u, &kd2a, &kd2b);

  const int gbN = (NN + 255) / 256;
  const int gbE = (NE + 255) / 256;
  const int gbScan = (NN + 1023) / 1024;
  const int gbGemm = (NN + 63) / 64;
  const int gbAgg = (NN + 3) / 4;

  k_init<<<gbN, 256, 0, stream>>>(cnt);
  k_hist<<<gbE, 256, 0, stream>>>(ei, cnt, slot);
  k_dinv<<<gbN, 256, 0, stream>>>(cnt, dinv);
  k_scan1<<<gbScan, 256, 0, stream>>>(cnt, rp, bsum);
  k_scan2<<<1, 64, 0, stream>>>(bsum, gbScan);
  k_scan3<<<gbN, 256, 0, stream>>>(rp, bsum);
  k_scatter<<<gbE, 256, 0, stream>>>(ei, rp, slot, csrc);

  k_gemm<128><<<gbGemm, 256, 0, stream>>>(x, W1, hb, NN);
  k_agg<128, true><<<gbAgg, 256, 0, stream>>>(hb, rp, csrc, dinv, b1, hf, kd1a, kd1b);
  k_gemm<128><<<gbGemm, 256, 0, stream>>>(hf, W2, hb, NN);
  k_agg<128, true><<<gbAgg, 256, 0, stream>>>(hb, rp, csrc, dinv, b2, hf, kd2a, kd2b);
  k_gemm<64><<<gbGemm, 256, 0, stream>>>(hf, W3, hb, NN);
  k_agg<64, false><<<gbAgg, 256, 0, stream>>>(hb, rp, csrc, dinv, b3, out, 0u, 0u);
}

// Round 6
// 418.304 us; speedup vs baseline: 1.9984x; 1.1747x over previous
//
#include <hip/hip_runtime.h>
#include <stdint.h>

#define NN 100000
#define NE 1600000

typedef float f4 __attribute__((ext_vector_type(4)));
typedef float f2 __attribute__((ext_vector_type(2)));
typedef unsigned short us4 __attribute__((ext_vector_type(4)));
typedef short s16x8 __attribute__((ext_vector_type(8)));

__device__ inline float bf2f(unsigned short u) {
  return __uint_as_float(((uint32_t)u) << 16);
}
__device__ inline unsigned short f2bf(float f) {  // round-to-nearest-even
  uint32_t u = __float_as_uint(f);
  return (unsigned short)((u + 0x7fffu + ((u >> 16) & 1u)) >> 16);
}
__device__ inline float lo16(uint32_t q) { return __uint_as_float(q << 16); }
__device__ inline float hi16(uint32_t q) { return __uint_as_float(q & 0xffff0000u); }

// Threefry-2x32, 20 rounds (Random123 / JAX exact).
__host__ __device__ inline void threefry2x32(uint32_t k0, uint32_t k1,
                                             uint32_t x0, uint32_t x1,
                                             uint32_t* y0, uint32_t* y1) {
  uint32_t ks[3] = {k0, k1, k0 ^ k1 ^ 0x1BD11BDAu};
  x0 += ks[0]; x1 += ks[1];
  const uint32_t R[2][4] = {{13u, 15u, 26u, 6u}, {17u, 29u, 16u, 24u}};
#pragma unroll
  for (int i = 0; i < 5; ++i) {
#pragma unroll
    for (int j = 0; j < 4; ++j) {
      uint32_t r = R[i & 1][j];
      x0 += x1;
      x1 = (x1 << r) | (x1 >> (32u - r));
      x1 ^= x0;
    }
    x0 += ks[(i + 1) % 3];
    x1 += ks[(i + 2) % 3] + (uint32_t)(i + 1);
  }
  *y0 = x0; *y1 = x1;
}

__device__ inline uint32_t tf_bits32(uint32_t k0, uint32_t k1, uint32_t idx) {
  uint32_t a, b;
  threefry2x32(k0, k1, 0u, idx, &a, &b);
  return a ^ b;
}

__global__ void k_init(uint32_t* cnt) {
  int i = blockIdx.x * 256 + threadIdx.x;
  if (i < NN) cnt[i] = 0u;
}

__global__ void k_hist(const int* __restrict__ ei, uint32_t* __restrict__ cnt,
                       int* __restrict__ slot) {
  int e = blockIdx.x * 256 + threadIdx.x;
  if (e < NE) {
    int d = ei[NE + e];
    slot[e] = (int)atomicAdd(&cnt[d], 1u);
  }
}

__global__ void k_dinv(const uint32_t* __restrict__ cnt, float* __restrict__ dinv) {
  int i = blockIdx.x * 256 + threadIdx.x;
  if (i < NN) dinv[i] = 1.0f / sqrtf((float)(cnt[i] + 1u));
}

__global__ __launch_bounds__(256) void k_scan1(const uint32_t* __restrict__ cnt,
                                               uint32_t* __restrict__ rp,
                                               uint32_t* __restrict__ bsum) {
  __shared__ uint32_t sh[256];
  int t = threadIdx.x;
  int base = blockIdx.x * 1024 + t * 4;
  uint32_t v[4];
  uint32_t s = 0;
#pragma unroll
  for (int i = 0; i < 4; ++i) {
    int idx = base + i;
    v[i] = (idx < NN) ? cnt[idx] : 0u;
    s += v[i];
  }
  sh[t] = s;
  __syncthreads();
  for (int off = 1; off < 256; off <<= 1) {
    uint32_t x = sh[t];
    if (t >= off) x += sh[t - off];
    __syncthreads();
    sh[t] = x;
    __syncthreads();
  }
  uint32_t run = (t > 0) ? sh[t - 1] : 0u;
  if (t == 255) bsum[blockIdx.x] = sh[255];
#pragma unroll
  for (int i = 0; i < 4; ++i) {
    int idx = base + i;
    if (idx < NN) rp[idx] = run;
    run += v[i];
  }
}

__global__ void k_scan2(uint32_t* bsum, int nb) {
  if (threadIdx.x == 0 && blockIdx.x == 0) {
    uint32_t s = 0;
    for (int i = 0; i < nb; ++i) { uint32_t x = bsum[i]; bsum[i] = s; s += x; }
  }
}

__global__ void k_scan3(uint32_t* rp, const uint32_t* __restrict__ bsum) {
  int i = blockIdx.x * 256 + threadIdx.x;
  if (i < NN) rp[i] += bsum[i >> 10];
  if (i == 0) rp[NN] = (uint32_t)NE;
}

__global__ void k_scatter(const int* __restrict__ ei,
                          const uint32_t* __restrict__ rp,
                          const int* __restrict__ slot,
                          int* __restrict__ csrc) {
  int e = blockIdx.x * 256 + threadIdx.x;
  if (e < NE) {
    int s = ei[e];
    int d = ei[NE + e];
    csrc[rp[d] + (uint32_t)slot[e]] = s;
  }
}

// x (f32) -> hi/lo bf16 arrays. Exactly NN*128/4 = 3.2M f4 elements.
__global__ void k_split(const float* __restrict__ A, unsigned short* __restrict__ H,
                        unsigned short* __restrict__ L) {
  int i = blockIdx.x * 256 + threadIdx.x;
  f4 v = ((const f4*)A)[i];
  us4 h, l;
#pragma unroll
  for (int j = 0; j < 4; ++j) {
    h[j] = f2bf(v[j]);
    l[j] = f2bf(v[j] - bf2f(h[j]));
  }
  ((us4*)H)[i] = h;
  ((us4*)L)[i] = l;
}

// W [128][dout] f32 -> packed MFMA B-frag layout, hi/lo:
// out[((ct*4+kk)*64 + lane)*8 + j] = W[kk*32 + (lane>>4)*8 + j][ct*16 + (lane&15)]
__global__ void k_wsplit(const float* __restrict__ W, int dout,
                         unsigned short* __restrict__ H,
                         unsigned short* __restrict__ L) {
  int lane = threadIdx.x;  // 64
  int kk = blockIdx.x & 3;
  int ct = blockIdx.x >> 2;
  int kbase = kk * 32 + (lane >> 4) * 8;
  int col = ct * 16 + (lane & 15);
  us4 h0, h1, l0, l1;
#pragma unroll
  for (int j = 0; j < 4; ++j) {
    float v = W[(size_t)(kbase + j) * dout + col];
    h0[j] = f2bf(v);
    l0[j] = f2bf(v - bf2f(h0[j]));
    float v2 = W[(size_t)(kbase + 4 + j) * dout + col];
    h1[j] = f2bf(v2);
    l1[j] = f2bf(v2 - bf2f(h1[j]));
  }
  size_t o = ((size_t)blockIdx.x * 64 + lane) * 8;
  *(us4*)(H + o) = h0; *(us4*)(H + o + 4) = h1;
  *(us4*)(L + o) = l0; *(us4*)(L + o + 4) = l1;
}

// C[NN x DOUT](bf16) = (Ah+Al)[NN x 128] @ (Wh+Wl)[128 x DOUT], split-bf16 MFMA.
// Block = 4 waves; wave w handles rows [blk*64 + 16w, +16), all DOUT cols.
// A/B frag layout: lane l holds 8 contiguous k = 8*(l>>4)+j, row/col = l&15.
// C/D layout (HW-verified): col = lane&15, row = (lane>>4)*4 + reg.
template <int DOUT>
__global__ __launch_bounds__(256) void k_gemm_mfma(
    const unsigned short* __restrict__ Ah, const unsigned short* __restrict__ Al,
    const unsigned short* __restrict__ Wh, const unsigned short* __restrict__ Wl,
    unsigned short* __restrict__ C) {
  constexpr int NT = DOUT / 16;
  const int w = threadIdx.x >> 6;
  const int lane = threadIdx.x & 63;
  const int row0 = blockIdx.x * 64 + w * 16;
  int ar = row0 + (lane & 15);
  if (ar >= NN) ar = NN - 1;  // clamp; stores are guarded
  const int aoff = (lane >> 4) * 8;
  s16x8 afh[4], afl[4];
#pragma unroll
  for (int kk = 0; kk < 4; ++kk) {
    afh[kk] = *(const s16x8*)(Ah + (size_t)ar * 128 + kk * 32 + aoff);
    afl[kk] = *(const s16x8*)(Al + (size_t)ar * 128 + kk * 32 + aoff);
  }
  f4 acc[NT];
#pragma unroll
  for (int t = 0; t < NT; ++t) acc[t] = (f4){0.f, 0.f, 0.f, 0.f};
#pragma unroll
  for (int ct = 0; ct < NT; ++ct) {
#pragma unroll
    for (int kk = 0; kk < 4; ++kk) {
      size_t bo = ((size_t)(ct * 4 + kk) * 64 + lane) * 8;
      s16x8 bh = *(const s16x8*)(Wh + bo);
      s16x8 bl = *(const s16x8*)(Wl + bo);
      acc[ct] = __builtin_amdgcn_mfma_f32_16x16x32_bf16(afh[kk], bh, acc[ct], 0, 0, 0);
      acc[ct] = __builtin_amdgcn_mfma_f32_16x16x32_bf16(afh[kk], bl, acc[ct], 0, 0, 0);
      acc[ct] = __builtin_amdgcn_mfma_f32_16x16x32_bf16(afl[kk], bh, acc[ct], 0, 0, 0);
    }
  }
  const int rbase = row0 + (lane >> 4) * 4;
  const int cbase = lane & 15;
#pragma unroll
  for (int ct = 0; ct < NT; ++ct) {
#pragma unroll
    for (int r = 0; r < 4; ++r) {
      int gr = rbase + r;
      if (gr < NN) C[(size_t)gr * DOUT + ct * 16 + cbase] = f2bf(acc[ct][r]);
    }
  }
}

// Middle aggregation (D=128): CSR gather-sum over bf16 h + self-loop + bias +
// ReLU + dropout; writes hi/lo bf16 split for the next MFMA GEMM.
// wid forced wave-uniform -> csrc/dinv reads become scalar (s_load) pipe ops.
__global__ __launch_bounds__(256) void k_agg_mid(
    const unsigned short* __restrict__ hb, const uint32_t* __restrict__ rp,
    const int* __restrict__ csrc, const float* __restrict__ dinv,
    const float* __restrict__ bias, unsigned short* __restrict__ oh,
    unsigned short* __restrict__ ol, uint32_t k0, uint32_t k1) {
  int wid = __builtin_amdgcn_readfirstlane(blockIdx.x * 4 + (threadIdx.x >> 6));
  if (wid >= NN) return;
  const int lane = threadIdx.x & 63;
  const uint32_t beg = rp[wid], end = rp[wid + 1];
  const float dv = dinv[wid];
  const float sn = dv * dv;
  const char* hbase = (const char*)hb;
  float a0 = 0.f, a1 = 0.f, c0 = 0.f, c1 = 0.f;
  uint32_t u = beg;
  for (; u + 4 <= end; u += 4) {
    int s0 = csrc[u], s1 = csrc[u + 1], s2 = csrc[u + 2], s3 = csrc[u + 3];
    float w0 = dinv[s0] * dv, w1 = dinv[s1] * dv;
    float w2 = dinv[s2] * dv, w3 = dinv[s3] * dv;
    uint32_t q0 = ((const uint32_t*)(hbase + ((size_t)(uint32_t)s0 << 8)))[lane];
    uint32_t q1 = ((const uint32_t*)(hbase + ((size_t)(uint32_t)s1 << 8)))[lane];
    uint32_t q2 = ((const uint32_t*)(hbase + ((size_t)(uint32_t)s2 << 8)))[lane];
    uint32_t q3 = ((const uint32_t*)(hbase + ((size_t)(uint32_t)s3 << 8)))[lane];
    a0 = fmaf(w0, lo16(q0), a0); a1 = fmaf(w0, hi16(q0), a1);
    c0 = fmaf(w1, lo16(q1), c0); c1 = fmaf(w1, hi16(q1), c1);
    a0 = fmaf(w2, lo16(q2), a0); a1 = fmaf(w2, hi16(q2), a1);
    c0 = fmaf(w3, lo16(q3), c0); c1 = fmaf(w3, hi16(q3), c1);
  }
  for (; u < end; ++u) {
    int s0 = csrc[u];
    float w0 = dinv[s0] * dv;
    uint32_t q0 = ((const uint32_t*)(hbase + ((size_t)(uint32_t)s0 << 8)))[lane];
    a0 = fmaf(w0, lo16(q0), a0); a1 = fmaf(w0, hi16(q0), a1);
  }
  a0 += c0; a1 += c1;
  uint32_t qs = ((const uint32_t*)(hbase + ((size_t)(uint32_t)wid << 8)))[lane];
  f2 bv = *(const f2*)(bias + lane * 2);
  a0 = fmaf(sn, lo16(qs), a0) + bv[0];
  a1 = fmaf(sn, hi16(qs), a1) + bv[1];
  a0 = fmaxf(a0, 0.f);
  a1 = fmaxf(a1, 0.f);
  uint32_t i0 = (uint32_t)wid * 128u + (uint32_t)lane * 2u;
  uint32_t m0 = tf_bits32(k0, k1, i0);
  uint32_t m1 = tf_bits32(k0, k1, i0 + 1u);
  a0 = (m0 & 0x80000000u) ? 0.f : a0 * 2.f;  // keep iff uniform < 0.5 iff MSB==0
  a1 = (m1 & 0x80000000u) ? 0.f : a1 * 2.f;
  unsigned short h0 = f2bf(a0), h1 = f2bf(a1);
  unsigned short g0 = f2bf(a0 - bf2f(h0)), g1 = f2bf(a1 - bf2f(h1));
  ((uint32_t*)oh)[(size_t)wid * 64 + lane] = (uint32_t)h0 | ((uint32_t)h1 << 16);
  ((uint32_t*)ol)[(size_t)wid * 64 + lane] = (uint32_t)g0 | ((uint32_t)g1 << 16);
}

// Final aggregation (D=64): gather-sum + self-loop + bias, f32 out.
__global__ __launch_bounds__(256) void k_agg_final(
    const unsigned short* __restrict__ hb, const uint32_t* __restrict__ rp,
    const int* __restrict__ csrc, const float* __restrict__ dinv,
    const float* __restrict__ bias, float* __restrict__ out) {
  int wid = __builtin_amdgcn_readfirstlane(blockIdx.x * 4 + (threadIdx.x >> 6));
  if (wid >= NN) return;
  const int lane = threadIdx.x & 63;
  const uint32_t beg = rp[wid], end = rp[wid + 1];
  const float dv = dinv[wid];
  const float sn = dv * dv;
  const char* hbase = (const char*)hb;
  float a0 = 0.f, c0 = 0.f, a2 = 0.f, c2 = 0.f;
  uint32_t u = beg;
  for (; u + 4 <= end; u += 4) {
    int s0 = csrc[u], s1 = csrc[u + 1], s2 = csrc[u + 2], s3 = csrc[u + 3];
    float w0 = dinv[s0] * dv, w1 = dinv[s1] * dv;
    float w2 = dinv[s2] * dv, w3 = dinv[s3] * dv;
    uint32_t q0 = (uint32_t)((const unsigned short*)(hbase + ((size_t)(uint32_t)s0 << 7)))[lane];
    uint32_t q1 = (uint32_t)((const unsigned short*)(hbase + ((size_t)(uint32_t)s1 << 7)))[lane];
    uint32_t q2 = (uint32_t)((const unsigned short*)(hbase + ((size_t)(uint32_t)s2 << 7)))[lane];
    uint32_t q3 = (uint32_t)((const unsigned short*)(hbase + ((size_t)(uint32_t)s3 << 7)))[lane];
    a0 = fmaf(w0, lo16(q0), a0);
    c0 = fmaf(w1, lo16(q1), c0);
    a2 = fmaf(w2, lo16(q2), a2);
    c2 = fmaf(w3, lo16(q3), c2);
  }
  for (; u < end; ++u) {
    int s0 = csrc[u];
    float w0 = dinv[s0] * dv;
    uint32_t q0 = (uint32_t)((const unsigned short*)(hbase + ((size_t)(uint32_t)s0 << 7)))[lane];
    a0 = fmaf(w0, lo16(q0), a0);
  }
  a0 += c0 + a2 + c2;
  uint32_t qs = (uint32_t)((const unsigned short*)(hbase + ((size_t)(uint32_t)wid << 7)))[lane];
  a0 = fmaf(sn, lo16(qs), a0) + bias[lane];
  out[(size_t)wid * 64 + lane] = a0;
}

extern "C" void kernel_launch(void* const* d_in, const int* in_sizes, int n_in,
                              void* d_out, int out_size, void* d_ws, size_t ws_size,
                              hipStream_t stream) {
  (void)in_sizes; (void)n_in; (void)out_size; (void)ws_size;
  const float* x  = (const float*)d_in[0];
  const float* W1 = (const float*)d_in[1];
  const float* b1 = (const float*)d_in[2];
  const float* W2 = (const float*)d_in[3];
  const float* b2 = (const float*)d_in[4];
  const float* W3 = (const float*)d_in[5];
  const float* b3 = (const float*)d_in[6];
  const int* ei   = (const int*)d_in[7];
  float* out = (float*)d_out;

  char* p = (char*)d_ws;
  auto alloc = [&](size_t bytes) -> void* {
    void* r = (void*)p;
    p += (bytes + 255) & ~(size_t)255;
    return r;
  };
  uint32_t* cnt  = (uint32_t*)alloc((size_t)NN * 4);
  float*    dinv = (float*)alloc((size_t)NN * 4);
  uint32_t* rp   = (uint32_t*)alloc((size_t)(NN + 1) * 4);
  uint32_t* bsum = (uint32_t*)alloc(1024);
  int*      slot = (int*)alloc((size_t)NE * 4);
  int*      csrc = (int*)alloc((size_t)NE * 4);
  unsigned short* ah = (unsigned short*)alloc((size_t)NN * 128 * 2);  // hi (x, then agg outs)
  unsigned short* al = (unsigned short*)alloc((size_t)NN * 128 * 2);  // lo
  unsigned short* hb = (unsigned short*)alloc((size_t)NN * 128 * 2);  // GEMM bf16 out (gathered)
  unsigned short* w1h = (unsigned short*)alloc(32 * 64 * 8 * 2);
  unsigned short* w1l = (unsigned short*)alloc(32 * 64 * 8 * 2);
  unsigned short* w2h = (unsigned short*)alloc(32 * 64 * 8 * 2);
  unsigned short* w2l = (unsigned short*)alloc(32 * 64 * 8 * 2);
  unsigned short* w3h = (unsigned short*)alloc(16 * 64 * 8 * 2);
  unsigned short* w3l = (unsigned short*)alloc(16 * 64 * 8 * 2);

  // JAX: kd1, kd2 = split(key(42)) — partitionable/fold-like split.
  uint32_t kd1a, kd1b, kd2a, kd2b;
  threefry2x32(0u, 42u, 0u, 0u, &kd1a, &kd1b);
  threefry2x32(0u, 42u, 0u, 1u, &kd2a, &kd2b);

  const int gbN = (NN + 255) / 256;
  const int gbE = (NE + 255) / 256;
  const int gbScan = (NN + 1023) / 1024;
  const int gbGemm = (NN + 63) / 64;   // 1563
  const int gbAgg = (NN + 3) / 4;      // 25000

  k_init<<<gbN, 256, 0, stream>>>(cnt);
  k_hist<<<gbE, 256, 0, stream>>>(ei, cnt, slot);
  k_dinv<<<gbN, 256, 0, stream>>>(cnt, dinv);
  k_scan1<<<gbScan, 256, 0, stream>>>(cnt, rp, bsum);
  k_scan2<<<1, 64, 0, stream>>>(bsum, gbScan);
  k_scan3<<<gbN, 256, 0, stream>>>(rp, bsum);
  k_scatter<<<gbE, 256, 0, stream>>>(ei, rp, slot, csrc);

  k_split<<<(NN * 128 / 4) / 256, 256, 0, stream>>>(x, ah, al);
  k_wsplit<<<32, 64, 0, stream>>>(W1, 128, w1h, w1l);
  k_wsplit<<<32, 64, 0, stream>>>(W2, 128, w2h, w2l);
  k_wsplit<<<16, 64, 0, stream>>>(W3, 64, w3h, w3l);

  k_gemm_mfma<128><<<gbGemm, 256, 0, stream>>>(ah, al, w1h, w1l, hb);
  k_agg_mid<<<gbAgg, 256, 0, stream>>>(hb, rp, csrc, dinv, b1, ah, al, kd1a, kd1b);
  k_gemm_mfma<128><<<gbGemm, 256, 0, stream>>>(ah, al, w2h, w2l, hb);
  k_agg_mid<<<gbAgg, 256, 0, stream>>>(hb, rp, csrc, dinv, b2, ah, al, kd2a, kd2b);
  k_gemm_mfma<64><<<gbGemm, 256, 0, stream>>>(ah, al, w3h, w3l, hb);
  k_agg_final<<<gbAgg, 256, 0, stream>>>(hb, rp, csrc, dinv, b3, out);
}